// Round 8
// baseline (190.140 us; speedup 1.0000x reference)
//
#include <hip/hip_runtime.h>
#include <math.h>

#define Bn 16
#define Sn 1024
#define Hn 1024
static const size_t SH = (size_t)Sn * Hn;          // 1,048,576
static const size_t BSH = (size_t)Bn * Sn * Hn;    // 16,777,216

typedef __attribute__((ext_vector_type(8))) short short8;
typedef __attribute__((ext_vector_type(4))) float f32x4;

// round-to-nearest-even fp32 -> bf16
__device__ __forceinline__ short bfr(float f) {
  union { float f; unsigned u; } v; v.f = f;
  unsigned r = (v.u + 0x7FFFu + ((v.u >> 16) & 1u)) >> 16;
  return (short)r;
}
__device__ __forceinline__ float b2f(unsigned short u) {
  union { unsigned u; float f; } v; v.u = (unsigned)u << 16; return v.f;
}
__device__ __forceinline__ short8 cvt8(float4 x, float4 y) {
  short8 r;
  r[0] = bfr(x.x); r[1] = bfr(x.y); r[2] = bfr(x.z); r[3] = bfr(x.w);
  r[4] = bfr(y.x); r[5] = bfr(y.y); r[6] = bfr(y.z); r[7] = bfr(y.w);
  return r;
}

// ---------------------------------------------------------------------------
// fused_cvt: enc[b][s][h] -> enc_bf (bf16, plain)  AND  encT[b][h][s] (plain)
// ---------------------------------------------------------------------------
__global__ __launch_bounds__(256) void fused_cvt_kernel(const float* __restrict__ enc,
                                                        short* __restrict__ enc_bf,
                                                        short* __restrict__ encT) {
  __shared__ float tile[64][65];
  const int b = blockIdx.z;
  const int s0 = blockIdx.y * 64, h0 = blockIdx.x * 64;
  const int t = threadIdx.x;
  const int tr = t >> 4, tc = t & 15;
  const float* src = enc + (size_t)b * SH;
#pragma unroll
  for (int i = 0; i < 4; ++i) {
    const int s = i * 16 + tr;
    const float4 v = *(const float4*)(src + (size_t)(s0 + s) * 1024 + h0 + tc * 4);
    tile[s][tc * 4 + 0] = v.x; tile[s][tc * 4 + 1] = v.y;
    tile[s][tc * 4 + 2] = v.z; tile[s][tc * 4 + 3] = v.w;
  }
  __syncthreads();
  // enc_bf: thread t -> local row t>>2, granules (t&3)*2 + {0,1}
  {
    const int rloc = t >> 2;
    const int rg = b * 1024 + s0 + rloc;
#pragma unroll
    for (int jj = 0; jj < 2; ++jj) {
      const int jloc = (t & 3) * 2 + jj;
      const float4 x = *(const float4*)&tile[rloc][jloc * 8];
      const float4 y = *(const float4*)&tile[rloc][jloc * 8 + 4];
      *(short8*)(enc_bf + (size_t)rg * 1024 + h0 + jloc * 8) = cvt8(x, y);
    }
  }
  // encT: thread t -> h row h0 + (t>>2), s-granules
  {
    const int hr = t >> 2, cs = t & 3;
    const int h = h0 + hr;
#pragma unroll
    for (int blk = 0; blk < 2; ++blk) {
      const int sg = blk * 4 + cs;
      const int gl = (s0 >> 3) + sg;
      short8 pk;
#pragma unroll
      for (int j = 0; j < 8; ++j) pk[j] = bfr(tile[sg * 8 + j][hr]);
      *(short8*)(encT + (size_t)b * SH + (size_t)h * 1024 + gl * 8) = pk;
    }
  }
}

// ---------------------------------------------------------------------------
// cvt_enc (tiny-ws fallback): enc -> enc_bf plain
// ---------------------------------------------------------------------------
__global__ __launch_bounds__(256) void cvt_enc_kernel(const float* __restrict__ enc,
                                                      short* __restrict__ enc_bf) {
  const int g = blockIdx.x * 256 + threadIdx.x;
  const int row = g >> 7;
  const int cs = g & 127;
  const float4 x = *(const float4*)(enc + (size_t)row * 1024 + cs * 8);
  const float4 y = *(const float4*)(enc + (size_t)row * 1024 + cs * 8 + 4);
  *(short8*)(enc_bf + (size_t)row * 1024 + cs * 8) = cvt8(x, y);
}

// ---------------------------------------------------------------------------
// cvt_w2: W_attn[h][1024..2047] -> W2_bf[h][k] bf16 plain
// ---------------------------------------------------------------------------
__global__ __launch_bounds__(256) void cvt_w2_kernel(const float* __restrict__ W_attn,
                                                     short* __restrict__ W2_bf) {
  const int g = blockIdx.x * 256 + threadIdx.x;
  const int h = g >> 7;
  const int cs = g & 127;
  const float4 x = *(const float4*)(W_attn + (size_t)h * 2048 + 1024 + cs * 8);
  const float4 y = *(const float4*)(W_attn + (size_t)h * 2048 + 1024 + cs * 8 + 4);
  *(short8*)(W2_bf + (size_t)h * 1024 + cs * 8) = cvt8(x, y);
}

// ---------------------------------------------------------------------------
// c1: c1[b,h] = ht[b,:] . W_attn[h, 0:H] + b_attn[h]   (grid Hn/4)
// ---------------------------------------------------------------------------
__global__ __launch_bounds__(256) void c1_kernel(const float* __restrict__ ht,
                                                 const float* __restrict__ W_attn,
                                                 const float* __restrict__ b_attn,
                                                 float* __restrict__ c1) {
  __shared__ float hts[16384];
  const int t = threadIdx.x;
#pragma unroll
  for (int i = 0; i < 16; ++i)
    *(float4*)&hts[i * 1024 + t * 4] = *(const float4*)&ht[i * 1024 + t * 4];
  __syncthreads();
  const int h = blockIdx.x * 4 + (t >> 6);
  const int lane = t & 63;
  const float* w = W_attn + (size_t)h * 2048;
  float s[16];
#pragma unroll
  for (int b = 0; b < 16; ++b) s[b] = 0.f;
  for (int k = lane; k < 1024; k += 64) {
    const float wv = w[k];
#pragma unroll
    for (int b = 0; b < 16; ++b) s[b] = fmaf(wv, hts[b * 1024 + k], s[b]);
  }
#pragma unroll
  for (int b = 0; b < 16; ++b) {
    float v = s[b];
#pragma unroll
    for (int off = 32; off; off >>= 1) v += __shfl_down(v, off, 64);
    if (lane == 0) c1[b * 1024 + h] = v + b_attn[h];
  }
}

// LDS slot for granule g (0..3) of row r, BK=32: R2-measured 0-conflict swizzle
#define LSLOT(r, g) ((r) * 32 + (((g) ^ (((r) >> 1) & 3)) << 3))

// ---------------------------------------------------------------------------
// GEMM1: Xbf = bf16(exp(tanh(enc_bf . W2_bf^T + c1))) + atomic colsum.
// 2-barrier skeleton (proven); staging = reg-prefetch (T14, context_fast-
// proven pattern): ds_write(cur from regs) -> load(next into regs) ->
// barrier -> ds_read+MFMA -> barrier. Plain global loads need no drain at
// the barrier, so latency hides under compute.
// ---------------------------------------------------------------------------
__global__ __launch_bounds__(256) void energy_v2(const short* __restrict__ enc_bf,
                                                 const short* __restrict__ W2_bf,
                                                 const float* __restrict__ c1,
                                                 short* __restrict__ Xbf,
                                                 float* __restrict__ colsum) {
  __shared__ __align__(16) short SM[16384];   // 32 KB: Ast 8K + Bst 8K; obuf reuses all
  short* Ast = SM;
  short* Bst = SM + 4096;
  const int flat = blockIdx.x + (blockIdx.y << 3) + (blockIdx.z << 6);
  const int swz = (flat & 7) * 128 + (flat >> 3);
  const int b = swz >> 6;
  const int row0 = ((swz >> 3) & 7) * 128;
  const int col0 = (swz & 7) * 128;
  const int t = threadIdx.x;
  const int l = t & 63;
  const int w = t >> 6;
  const int wr = w >> 1, wc = w & 1;
  const int fr = l & 15, kg = l >> 4;

  // staging: thread t -> row t>>1, granules (t&1)*2 + {0,1}
  const int sr = t >> 1;
  const int sc0 = (t & 1) * 2;
  const short* aptr = enc_bf + (size_t)b * SH + (size_t)(row0 + sr) * 1024 + sc0 * 8;
  const short* bptr = W2_bf + (size_t)(col0 + sr) * 1024 + sc0 * 8;
  const int sl0 = LSLOT(sr, sc0);
  const int sl1 = LSLOT(sr, sc0 + 1);

  short8 pa0 = *(const short8*)(aptr);
  short8 pa1 = *(const short8*)(aptr + 8);
  short8 pb0 = *(const short8*)(bptr);
  short8 pb1 = *(const short8*)(bptr + 8);

  f32x4 acc[4][4] = {};

  for (int k0 = 0; k0 < 1024; k0 += 32) {
    *(short8*)&Ast[sl0] = pa0;
    *(short8*)&Ast[sl1] = pa1;
    *(short8*)&Bst[sl0] = pb0;
    *(short8*)&Bst[sl1] = pb1;
    if (k0 != 992) {
      pa0 = *(const short8*)(aptr + k0 + 32);
      pa1 = *(const short8*)(aptr + k0 + 40);
      pb0 = *(const short8*)(bptr + k0 + 32);
      pb1 = *(const short8*)(bptr + k0 + 40);
    }
    __syncthreads();   // lgkm drained: tile visible; reg loads stay in flight
    short8 af[4], bf4[4];
#pragma unroll
    for (int m = 0; m < 4; ++m) {
      const int r = wr * 64 + m * 16 + fr;
      af[m] = *(const short8*)&Ast[LSLOT(r, kg)];
    }
#pragma unroll
    for (int n = 0; n < 4; ++n) {
      const int r = wc * 64 + n * 16 + fr;
      bf4[n] = *(const short8*)&Bst[LSLOT(r, kg)];
    }
#pragma unroll
    for (int m = 0; m < 4; ++m)
#pragma unroll
      for (int n = 0; n < 4; ++n)
        acc[m][n] = __builtin_amdgcn_mfma_f32_16x16x32_bf16(af[m], bf4[n], acc[m][n], 0, 0, 0);
    __syncthreads();   // reads done before next ds_write
  }

  // epilogue: X = exp(tanh(acc+c1)); obuf (LDS, granule-XOR for banks);
  // colsum partials reduced over kg lanes then one atomicAdd per col.
  unsigned short* obuf = (unsigned short*)SM;
#pragma unroll
  for (int n = 0; n < 4; ++n) {
    const int col_loc = wc * 64 + n * 16 + fr;
    const float c1v = c1[b * 1024 + col0 + col_loc];
    float csum = 0.f;
#pragma unroll
    for (int m = 0; m < 4; ++m) {
      const int rbase = wr * 64 + m * 16 + kg * 4;
#pragma unroll
      for (int r = 0; r < 4; ++r) {
        const float x = acc[m][n][r] + c1v;
        const float e = __expf(2.f * x);
        const float X = __expf((e - 1.f) / (e + 1.f));
        csum += X;
        const int row = rbase + r;
        obuf[row * 128 + (col_loc ^ ((row & 7) << 3))] = (unsigned short)bfr(X);
      }
    }
    csum += __shfl_xor(csum, 16);
    csum += __shfl_xor(csum, 32);
    if (l < 16) atomicAdd(&colsum[b * 1024 + col0 + col_loc], csum);
  }
  __syncthreads();
  // copy-out: logical granule g stored at g ^ (row&7); global is plain
  const int orow = t >> 1;
  short* gdst = Xbf + (size_t)b * SH + (size_t)(row0 + orow) * 1024 + col0;
#pragma unroll
  for (int j = 0; j < 8; ++j) {
    const int slot = (t & 1) * 8 + j;
    *(short8*)(gdst + slot * 8) = *(short8*)&obuf[orow * 128 + ((slot ^ (orow & 7)) << 3)];
  }
}

// ---------------------------------------------------------------------------
// rcp: colinv = 1/colsum
// ---------------------------------------------------------------------------
__global__ __launch_bounds__(256) void rcp_kernel(const float* __restrict__ cs,
                                                  float* __restrict__ ci) {
  const int i = blockIdx.x * 256 + threadIdx.x;
  ci[i] = 1.0f / cs[i];
}

// ---------------------------------------------------------------------------
// scale: awbf = bf16(Xbf * colinv) in-place (plain layout), aw fp32 out
// ---------------------------------------------------------------------------
__global__ __launch_bounds__(256) void scale_v1(short* __restrict__ Xbf,
                                                const float* __restrict__ colinv,
                                                float* __restrict__ aw) {
  const size_t gid = (size_t)blockIdx.x * 256 + threadIdx.x;
  const int rg = (int)(gid >> 7);
  const int gl = (int)(gid & 127);
  const int b = rg >> 10;
  const int h0 = gl * 8;
  short* p = Xbf + (size_t)rg * 1024 + h0;
  const short8 v = *(const short8*)p;
  const float4 ci0 = *(const float4*)(colinv + (b << 10) + h0);
  const float4 ci1 = *(const float4*)(colinv + (b << 10) + h0 + 4);
  float f[8];
  f[0] = b2f((unsigned short)v[0]) * ci0.x; f[1] = b2f((unsigned short)v[1]) * ci0.y;
  f[2] = b2f((unsigned short)v[2]) * ci0.z; f[3] = b2f((unsigned short)v[3]) * ci0.w;
  f[4] = b2f((unsigned short)v[4]) * ci1.x; f[5] = b2f((unsigned short)v[5]) * ci1.y;
  f[6] = b2f((unsigned short)v[6]) * ci1.z; f[7] = b2f((unsigned short)v[7]) * ci1.w;
  float4 o0 = {f[0], f[1], f[2], f[3]};
  float4 o1 = {f[4], f[5], f[6], f[7]};
  *(float4*)(aw + (size_t)rg * 1024 + h0) = o0;
  *(float4*)(aw + (size_t)rg * 1024 + h0 + 4) = o1;
  short8 r;
#pragma unroll
  for (int j = 0; j < 8; ++j) r[j] = bfr(f[j]);
  *(short8*)p = r;
}

// ---------------------------------------------------------------------------
// GEMM2: ctx = awbf . encT^T — same reg-prefetch 2-barrier template
// ---------------------------------------------------------------------------
__global__ __launch_bounds__(256) void context_v2(const short* __restrict__ awbf,
                                                  const short* __restrict__ encT,
                                                  float* __restrict__ ctx) {
  __shared__ __align__(16) short SM[8192];   // Ast 8K + Bst 8K
  short* Ast = SM;
  short* Bst = SM + 4096;
  const int flat = blockIdx.x + (blockIdx.y << 3) + (blockIdx.z << 6);
  const int swz = (flat & 7) * 128 + (flat >> 3);
  const int b = swz >> 6;
  const int row0 = ((swz >> 3) & 7) * 128;
  const int col0 = (swz & 7) * 128;
  const int t = threadIdx.x;
  const int l = t & 63;
  const int w = t >> 6;
  const int wr = w >> 1, wc = w & 1;
  const int fr = l & 15, kg = l >> 4;

  const int sr = t >> 1;
  const int sc0 = (t & 1) * 2;
  const short* aptr = awbf + (size_t)b * SH + (size_t)(row0 + sr) * 1024 + sc0 * 8;
  const short* bptr = encT + (size_t)b * SH + (size_t)(col0 + sr) * 1024 + sc0 * 8;
  const int sl0 = LSLOT(sr, sc0);
  const int sl1 = LSLOT(sr, sc0 + 1);

  short8 pa0 = *(const short8*)(aptr);
  short8 pa1 = *(const short8*)(aptr + 8);
  short8 pb0 = *(const short8*)(bptr);
  short8 pb1 = *(const short8*)(bptr + 8);

  f32x4 acc[4][4] = {};

  for (int k0 = 0; k0 < 1024; k0 += 32) {
    *(short8*)&Ast[sl0] = pa0;
    *(short8*)&Ast[sl1] = pa1;
    *(short8*)&Bst[sl0] = pb0;
    *(short8*)&Bst[sl1] = pb1;
    if (k0 != 992) {
      pa0 = *(const short8*)(aptr + k0 + 32);
      pa1 = *(const short8*)(aptr + k0 + 40);
      pb0 = *(const short8*)(bptr + k0 + 32);
      pb1 = *(const short8*)(bptr + k0 + 40);
    }
    __syncthreads();
    short8 af[4], bf4[4];
#pragma unroll
    for (int m = 0; m < 4; ++m) {
      const int r = wr * 64 + m * 16 + fr;
      af[m] = *(const short8*)&Ast[LSLOT(r, kg)];
    }
#pragma unroll
    for (int n = 0; n < 4; ++n) {
      const int r = wc * 64 + n * 16 + fr;
      bf4[n] = *(const short8*)&Bst[LSLOT(r, kg)];
    }
#pragma unroll
    for (int m = 0; m < 4; ++m)
#pragma unroll
      for (int n = 0; n < 4; ++n)
        acc[m][n] = __builtin_amdgcn_mfma_f32_16x16x32_bf16(af[m], bf4[n], acc[m][n], 0, 0, 0);
    __syncthreads();
  }

  float* Cb = ctx + (size_t)b * SH;
#pragma unroll
  for (int n = 0; n < 4; ++n) {
    const int col = col0 + wc * 64 + n * 16 + fr;
#pragma unroll
    for (int m = 0; m < 4; ++m) {
      const int r0 = row0 + wr * 64 + m * 16 + kg * 4;
#pragma unroll
      for (int r = 0; r < 4; ++r)
        Cb[(size_t)(r0 + r) * 1024 + col] = acc[m][n][r];
    }
  }
}

// ===========================================================================
// Fallback kernels (ws-limited paths)
// ===========================================================================
// energy fp32-out (same loop, fp32 strided epilogue)
__global__ __launch_bounds__(256) void energy_v2f(const short* __restrict__ enc_bf,
                                                  const short* __restrict__ W2_bf,
                                                  const float* __restrict__ c1,
                                                  float* __restrict__ X) {
  __shared__ __align__(16) short SM[8192];
  short* Ast = SM;
  short* Bst = SM + 4096;
  const int flat = blockIdx.x + (blockIdx.y << 3) + (blockIdx.z << 6);
  const int swz = (flat & 7) * 128 + (flat >> 3);
  const int b = swz >> 6;
  const int row0 = ((swz >> 3) & 7) * 128;
  const int col0 = (swz & 7) * 128;
  const int t = threadIdx.x;
  const int l = t & 63;
  const int w = t >> 6;
  const int wr = w >> 1, wc = w & 1;
  const int fr = l & 15, kg = l >> 4;

  const int sr = t >> 1;
  const int sc0 = (t & 1) * 2;
  const short* aptr = enc_bf + (size_t)b * SH + (size_t)(row0 + sr) * 1024 + sc0 * 8;
  const short* bptr = W2_bf + (size_t)(col0 + sr) * 1024 + sc0 * 8;
  const int sl0 = LSLOT(sr, sc0);
  const int sl1 = LSLOT(sr, sc0 + 1);

  short8 pa0 = *(const short8*)(aptr);
  short8 pa1 = *(const short8*)(aptr + 8);
  short8 pb0 = *(const short8*)(bptr);
  short8 pb1 = *(const short8*)(bptr + 8);

  f32x4 acc[4][4] = {};

  for (int k0 = 0; k0 < 1024; k0 += 32) {
    *(short8*)&Ast[sl0] = pa0;
    *(short8*)&Ast[sl1] = pa1;
    *(short8*)&Bst[sl0] = pb0;
    *(short8*)&Bst[sl1] = pb1;
    if (k0 != 992) {
      pa0 = *(const short8*)(aptr + k0 + 32);
      pa1 = *(const short8*)(aptr + k0 + 40);
      pb0 = *(const short8*)(bptr + k0 + 32);
      pb1 = *(const short8*)(bptr + k0 + 40);
    }
    __syncthreads();
    short8 af[4], bf4[4];
#pragma unroll
    for (int m = 0; m < 4; ++m) {
      const int r = wr * 64 + m * 16 + fr;
      af[m] = *(const short8*)&Ast[LSLOT(r, kg)];
    }
#pragma unroll
    for (int n = 0; n < 4; ++n) {
      const int r = wc * 64 + n * 16 + fr;
      bf4[n] = *(const short8*)&Bst[LSLOT(r, kg)];
    }
#pragma unroll
    for (int m = 0; m < 4; ++m)
#pragma unroll
      for (int n = 0; n < 4; ++n)
        acc[m][n] = __builtin_amdgcn_mfma_f32_16x16x32_bf16(af[m], bf4[n], acc[m][n], 0, 0, 0);
    __syncthreads();
  }

  float* Xb = X + (size_t)b * SH;
#pragma unroll
  for (int n = 0; n < 4; ++n) {
    const int col = col0 + wc * 64 + n * 16 + fr;
    const float c1v = c1[b * 1024 + col];
#pragma unroll
    for (int m = 0; m < 4; ++m) {
      const int r0 = row0 + wr * 64 + m * 16 + kg * 4;
#pragma unroll
      for (int r = 0; r < 4; ++r) {
        const float x = acc[m][n][r] + c1v;
        const float e = __expf(2.f * x);
        Xb[(size_t)(r0 + r) * 1024 + col] = __expf((e - 1.f) / (e + 1.f));
      }
    }
  }
}

__global__ __launch_bounds__(256) void norm_kernel(float* __restrict__ X) {
  const int b = blockIdx.x >> 4;
  const int hg = blockIdx.x & 15;
  const int l = threadIdx.x & 63;
  const int sg = threadIdx.x >> 6;
  float* col = X + (size_t)b * SH + hg * 64 + l;
  const int s0 = sg * 256;
  float sum = 0.f;
#pragma unroll 8
  for (int s = s0; s < s0 + 256; ++s) sum += col[(size_t)s * 1024];
  __shared__ float red[4][64];
  red[sg][l] = sum;
  __syncthreads();
  const float inv = 1.f / (red[0][l] + red[1][l] + red[2][l] + red[3][l]);
#pragma unroll 8
  for (int s = s0; s < s0 + 256; ++s) col[(size_t)s * 1024] *= inv;
}

// ws1 fallback GEMM2: A from fp32 aw (reg-staged + cvt), B encT plain
__global__ __launch_bounds__(256) void context_fast2(const float* __restrict__ aw,
                                                     const short* __restrict__ encT,
                                                     float* __restrict__ ctx) {
  __shared__ __align__(16) short SM[8192];
  short* Ast = SM;
  short* Bst = SM + 4096;
  const int flat = blockIdx.x + (blockIdx.y << 3) + (blockIdx.z << 6);
  const int swz = (flat & 7) * 128 + (flat >> 3);
  const int b = swz >> 6;
  const int row0 = ((swz >> 3) & 7) * 128;
  const int col0 = (swz & 7) * 128;
  const int t = threadIdx.x;
  const int l = t & 63;
  const int w = t >> 6;
  const int wr = w >> 1, wc = w & 1;
  const int fr = l & 15, kg = l >> 4;

  const int sr = t >> 1;
  const int sc0 = (t & 1) * 2;
  const float* aptr = aw + (size_t)b * SH + (size_t)(row0 + sr) * 1024 + sc0 * 8;
  const short* bptr = encT + (size_t)b * SH + (size_t)(col0 + sr) * 1024 + sc0 * 8;
  const int sl0 = LSLOT(sr, sc0);
  const int sl1 = LSLOT(sr, sc0 + 1);

  float4 fa0 = *(const float4*)(aptr);
  float4 fa1 = *(const float4*)(aptr + 4);
  float4 fa2 = *(const float4*)(aptr + 8);
  float4 fa3 = *(const float4*)(aptr + 12);
  short8 pb0 = *(const short8*)(bptr);
  short8 pb1 = *(const short8*)(bptr + 8);

  f32x4 acc[4][4] = {};

  for (int k0 = 0; k0 < 1024; k0 += 32) {
    *(short8*)&Ast[sl0] = cvt8(fa0, fa1);
    *(short8*)&Ast[sl1] = cvt8(fa2, fa3);
    *(short8*)&Bst[sl0] = pb0;
    *(short8*)&Bst[sl1] = pb1;
    if (k0 != 992) {
      fa0 = *(const float4*)(aptr + k0 + 32);
      fa1 = *(const float4*)(aptr + k0 + 36);
      fa2 = *(const float4*)(aptr + k0 + 40);
      fa3 = *(const float4*)(aptr + k0 + 44);
      pb0 = *(const short8*)(bptr + k0 + 32);
      pb1 = *(const short8*)(bptr + k0 + 40);
    }
    __syncthreads();
    short8 af[4], bf4[4];
#pragma unroll
    for (int m = 0; m < 4; ++m) {
      const int r = wr * 64 + m * 16 + fr;
      af[m] = *(const short8*)&Ast[LSLOT(r, kg)];
    }
#pragma unroll
    for (int n = 0; n < 4; ++n) {
      const int r = wc * 64 + n * 16 + fr;
      bf4[n] = *(const short8*)&Bst[LSLOT(r, kg)];
    }
#pragma unroll
    for (int m = 0; m < 4; ++m)
#pragma unroll
      for (int n = 0; n < 4; ++n)
        acc[m][n] = __builtin_amdgcn_mfma_f32_16x16x32_bf16(af[m], bf4[n], acc[m][n], 0, 0, 0);
    __syncthreads();
  }

  float* Cb = ctx + (size_t)b * SH;
#pragma unroll
  for (int n = 0; n < 4; ++n) {
    const int col = col0 + wc * 64 + n * 16 + fr;
#pragma unroll
    for (int m = 0; m < 4; ++m) {
      const int r0 = row0 + wr * 64 + m * 16 + kg * 4;
#pragma unroll
      for (int r = 0; r < 4; ++r)
        Cb[(size_t)(r0 + r) * 1024 + col] = acc[m][n][r];
    }
  }
}

// ws0 fallback GEMM2: self-contained (reads raw fp32 enc, transposes in LDS)
__global__ __launch_bounds__(256) void context_mfma(const float* __restrict__ aw,
                                                    const float* __restrict__ enc,
                                                    float* __restrict__ ctx) {
  __shared__ __align__(16) short Ast[128 * 32];
  __shared__ __align__(16) short Bst[128 * 32];
  const int b = blockIdx.z;
  const int row0 = blockIdx.y * 128;
  const int col0 = blockIdx.x * 128;
  const int t = threadIdx.x;
  const int l = t & 63;
  const int w = t >> 6;
  const int wr = w >> 1, wc = w & 1;
  const int fr = l & 15, kg = l >> 4;

  const int sr = t >> 1;
  const int sc0 = (t & 1) * 2;
  const float* arow = aw + (size_t)b * SH + (size_t)(row0 + sr) * 1024;
  const int bcol = t & 127;
  const int kb0 = (t >> 7) * 2;
  const float* bcolp = enc + (size_t)b * SH + col0 + bcol;

  f32x4 acc[4][4] = {};

  for (int k0 = 0; k0 < 1024; k0 += 32) {
    const float4 a0 = *(const float4*)(arow + k0 + sc0 * 8);
    const float4 a1 = *(const float4*)(arow + k0 + sc0 * 8 + 4);
    const float4 a2 = *(const float4*)(arow + k0 + sc0 * 8 + 8);
    const float4 a3 = *(const float4*)(arow + k0 + sc0 * 8 + 12);
    float bv[2][8];
#pragma unroll
    for (int j = 0; j < 2; ++j)
#pragma unroll
      for (int i = 0; i < 8; ++i)
        bv[j][i] = bcolp[(size_t)(k0 + (kb0 + j) * 8 + i) * 1024];
    __syncthreads();
    *(short8*)&Ast[LSLOT(sr, sc0)]     = cvt8(a0, a1);
    *(short8*)&Ast[LSLOT(sr, sc0 + 1)] = cvt8(a2, a3);
#pragma unroll
    for (int j = 0; j < 2; ++j) {
      short8 pk;
#pragma unroll
      for (int i = 0; i < 8; ++i) pk[i] = bfr(bv[j][i]);
      *(short8*)&Bst[LSLOT(bcol, kb0 + j)] = pk;
    }
    __syncthreads();
    short8 af[4], bf4[4];
#pragma unroll
    for (int m = 0; m < 4; ++m) {
      const int r = wr * 64 + m * 16 + fr;
      af[m] = *(const short8*)&Ast[LSLOT(r, kg)];
    }
#pragma unroll
    for (int n = 0; n < 4; ++n) {
      const int r = wc * 64 + n * 16 + fr;
      bf4[n] = *(const short8*)&Bst[LSLOT(r, kg)];
    }
#pragma unroll
    for (int m = 0; m < 4; ++m)
#pragma unroll
      for (int n = 0; n < 4; ++n)
        acc[m][n] = __builtin_amdgcn_mfma_f32_16x16x32_bf16(af[m], bf4[n], acc[m][n], 0, 0, 0);
  }

  float* Cb = ctx + (size_t)b * SH;
#pragma unroll
  for (int n = 0; n < 4; ++n) {
    const int col = col0 + wc * 64 + n * 16 + fr;
#pragma unroll
    for (int m = 0; m < 4; ++m) {
      const int r0 = row0 + wr * 64 + m * 16 + kg * 4;
#pragma unroll
      for (int r = 0; r < 4; ++r)
        Cb[(size_t)(r0 + r) * 1024 + col] = acc[m][n][r];
    }
  }
}

// ---------------------------------------------------------------------------
extern "C" void kernel_launch(void* const* d_in, const int* in_sizes, int n_in,
                              void* d_out, int out_size, void* d_ws, size_t ws_size,
                              hipStream_t stream) {
  (void)in_sizes; (void)n_in; (void)out_size;
  const float* ht     = (const float*)d_in[0];
  const float* enc    = (const float*)d_in[1];
  const float* W_attn = (const float*)d_in[2];
  const float* b_attn = (const float*)d_in[3];
  // d_in[4] (W_v) is dead code in the reference

  float* ctx = (float*)d_out;          // [B,S,H] context (written last)
  float* aw  = ctx + BSH;              // [B,S,H] attention_weights

  // scratch parked inside the (dead-until-GEMM2) ctx region:
  short* enc_bf = (short*)ctx;                         // 32 MB, bf16 plain
  short* W2_bf  = (short*)(ctx + 8388608);             // 2 MB
  float* c1f    = ctx + 8912896;                       // 64 KB
  float* colsum = c1f + 16384;                         // 64 KB
  float* colinv = c1f + 32768;                         // 64 KB

  const bool ws1 = ws_size >= ((size_t)32 << 20);                 // encT
  const bool ws2 = ws_size >= ((size_t)64 << 20);                 // + Xbf
  short* encT = (short*)d_ws;                                     // 32 MB
  short* Xbf  = (short*)((char*)d_ws + ((size_t)32 << 20));       // 32 MB

  cvt_w2_kernel<<<512, 256, 0, stream>>>(W_attn, W2_bf);
  c1_kernel<<<Hn / 4, 256, 0, stream>>>(ht, W_attn, b_attn, c1f);

  if (ws1) {
    dim3 gt(16, 16, Bn);
    fused_cvt_kernel<<<gt, 256, 0, stream>>>(enc, enc_bf, encT);
  } else {
    cvt_enc_kernel<<<8192, 256, 0, stream>>>(enc, enc_bf);
  }

  dim3 g(8, 8, Bn);
  if (ws2) {
    hipMemsetAsync(colsum, 0, 65536, stream);
    energy_v2<<<g, 256, 0, stream>>>(enc_bf, W2_bf, c1f, Xbf, colsum);
    rcp_kernel<<<64, 256, 0, stream>>>(colsum, colinv);
    scale_v1<<<8192, 256, 0, stream>>>(Xbf, colinv, aw);
    context_v2<<<g, 256, 0, stream>>>(Xbf, encT, ctx);
  } else {
    energy_v2f<<<g, 256, 0, stream>>>(enc_bf, W2_bf, c1f, aw);
    norm_kernel<<<Bn * 16, 256, 0, stream>>>(aw);
    if (ws1)
      context_fast2<<<g, 256, 0, stream>>>(aw, encT, ctx);
    else
      context_mfma<<<g, 256, 0, stream>>>(aw, enc, ctx);
  }
}

// Round 9
// 168.730 us; speedup vs baseline: 1.1269x; 1.1269x over previous
//
#include <hip/hip_runtime.h>
#include <math.h>

#define Bn 16
#define Sn 1024
#define Hn 1024
static const size_t SH = (size_t)Sn * Hn;          // 1,048,576
static const size_t BSH = (size_t)Bn * Sn * Hn;    // 16,777,216

typedef __attribute__((ext_vector_type(8))) short short8;
typedef __attribute__((ext_vector_type(4))) float f32x4;

// async global->LDS, 16B per lane; LDS dest is wave-uniform base + lane*16
#define GLD16(gp, lp) __builtin_amdgcn_global_load_lds( \
    (const __attribute__((address_space(1))) void*)(gp), \
    (__attribute__((address_space(3))) void*)(lp), 16, 0, 0)

// round-to-nearest-even fp32 -> bf16
__device__ __forceinline__ short bfr(float f) {
  union { float f; unsigned u; } v; v.f = f;
  unsigned r = (v.u + 0x7FFFu + ((v.u >> 16) & 1u)) >> 16;
  return (short)r;
}
__device__ __forceinline__ float b2f(unsigned short u) {
  union { unsigned u; float f; } v; v.u = (unsigned)u << 16; return v.f;
}
__device__ __forceinline__ short8 cvt8(float4 x, float4 y) {
  short8 r;
  r[0] = bfr(x.x); r[1] = bfr(x.y); r[2] = bfr(x.z); r[3] = bfr(x.w);
  r[4] = bfr(y.x); r[5] = bfr(y.y); r[6] = bfr(y.z); r[7] = bfr(y.w);
  return r;
}

// 8-granule swizzle: storage slot of logical granule g in row `row` is
// g ^ (row&7) within each 8-granule (64-element) k-block. Involution.
__device__ __forceinline__ int swz8(int row, int g) {
  return (g & ~7) | ((g & 7) ^ (row & 7));
}

// ---------------------------------------------------------------------------
// fused_cvt: enc[b][s][h] -> enc_bf (bf16, swz8 rows)  AND  encT (swz8 rows)
// ---------------------------------------------------------------------------
__global__ __launch_bounds__(256) void fused_cvt_kernel(const float* __restrict__ enc,
                                                        short* __restrict__ enc_bf,
                                                        short* __restrict__ encT) {
  __shared__ float tile[64][65];
  const int b = blockIdx.z;
  const int s0 = blockIdx.y * 64, h0 = blockIdx.x * 64;
  const int t = threadIdx.x;
  const int tr = t >> 4, tc = t & 15;
  const float* src = enc + (size_t)b * SH;
#pragma unroll
  for (int i = 0; i < 4; ++i) {
    const int s = i * 16 + tr;
    const float4 v = *(const float4*)(src + (size_t)(s0 + s) * 1024 + h0 + tc * 4);
    tile[s][tc * 4 + 0] = v.x; tile[s][tc * 4 + 1] = v.y;
    tile[s][tc * 4 + 2] = v.z; tile[s][tc * 4 + 3] = v.w;
  }
  __syncthreads();
  {
    const int rloc = t >> 2;
    const int rg = b * 1024 + s0 + rloc;
#pragma unroll
    for (int jj = 0; jj < 2; ++jj) {
      const int jloc = (t & 3) * 2 + jj;
      const int slot = jloc ^ (rg & 7);
      const float4 x = *(const float4*)&tile[rloc][jloc * 8];
      const float4 y = *(const float4*)&tile[rloc][jloc * 8 + 4];
      *(short8*)(enc_bf + (size_t)rg * 1024 + h0 + slot * 8) = cvt8(x, y);
    }
  }
  {
    const int hr = t >> 2, cs = t & 3;
    const int h = h0 + hr;
#pragma unroll
    for (int blk = 0; blk < 2; ++blk) {
      const int sg = blk * 4 + cs;
      const int gl = (s0 >> 3) + sg;
      const int gst = swz8(h, gl);
      short8 pk;
#pragma unroll
      for (int j = 0; j < 8; ++j) pk[j] = bfr(tile[sg * 8 + j][hr]);
      *(short8*)(encT + (size_t)b * SH + (size_t)h * 1024 + gst * 8) = pk;
    }
  }
}

// ---------------------------------------------------------------------------
// cvt_enc (fallback): enc -> enc_bf, swz8
// ---------------------------------------------------------------------------
__global__ __launch_bounds__(256) void cvt_enc_kernel(const float* __restrict__ enc,
                                                      short* __restrict__ enc_bf) {
  const int g = blockIdx.x * 256 + threadIdx.x;
  const int row = g >> 7;
  const int cs = g & 127;
  const float4 x = *(const float4*)(enc + (size_t)row * 1024 + cs * 8);
  const float4 y = *(const float4*)(enc + (size_t)row * 1024 + cs * 8 + 4);
  *(short8*)(enc_bf + (size_t)row * 1024 + swz8(row, cs) * 8) = cvt8(x, y);
}

// ---------------------------------------------------------------------------
// cvt_w2: W_attn[h][1024..2047] -> W2_bf[h][k] bf16, swz8
// ---------------------------------------------------------------------------
__global__ __launch_bounds__(256) void cvt_w2_kernel(const float* __restrict__ W_attn,
                                                     short* __restrict__ W2_bf) {
  const int g = blockIdx.x * 256 + threadIdx.x;
  const int h = g >> 7;
  const int cs = g & 127;
  const float4 x = *(const float4*)(W_attn + (size_t)h * 2048 + 1024 + cs * 8);
  const float4 y = *(const float4*)(W_attn + (size_t)h * 2048 + 1024 + cs * 8 + 4);
  *(short8*)(W2_bf + (size_t)h * 1024 + swz8(h, cs) * 8) = cvt8(x, y);
}

// ---------------------------------------------------------------------------
// c1: c1[b,h] = ht[b,:] . W_attn[h, 0:H] + b_attn[h]   (grid Hn/4)
// ---------------------------------------------------------------------------
__global__ __launch_bounds__(256) void c1_kernel(const float* __restrict__ ht,
                                                 const float* __restrict__ W_attn,
                                                 const float* __restrict__ b_attn,
                                                 float* __restrict__ c1) {
  __shared__ float hts[16384];
  const int t = threadIdx.x;
#pragma unroll
  for (int i = 0; i < 16; ++i)
    *(float4*)&hts[i * 1024 + t * 4] = *(const float4*)&ht[i * 1024 + t * 4];
  __syncthreads();
  const int h = blockIdx.x * 4 + (t >> 6);
  const int lane = t & 63;
  const float* w = W_attn + (size_t)h * 2048;
  float s[16];
#pragma unroll
  for (int b = 0; b < 16; ++b) s[b] = 0.f;
  for (int k = lane; k < 1024; k += 64) {
    const float wv = w[k];
#pragma unroll
    for (int b = 0; b < 16; ++b) s[b] = fmaf(wv, hts[b * 1024 + k], s[b]);
  }
#pragma unroll
  for (int b = 0; b < 16; ++b) {
    float v = s[b];
#pragma unroll
    for (int off = 32; off; off >>= 1) v += __shfl_down(v, off, 64);
    if (lane == 0) c1[b * 1024 + h] = v + b_attn[h];
  }
}

// ===========================================================================
// 8-phase 256x256 GEMM template (m201-style, plain HIP).
// 512 thr = 8 waves (2 wr x 4 wc); BK=64; LDS 128KB = 2 dbuf x (A 32K + B 32K).
// A region mh: rows {wr*128+mh*64+r}; B region nh: cols {wc*64+nh*32+c}.
// Phase (mh,nh): 16 MFMA. Stage schedule (tile kt): p0->B1(kt+1), p1->A1(kt+1),
// p2->A0(kt+2), p3->B0(kt+2). vmcnt(4) once per tile (boundary); raw barriers
// keep stages in flight. Global operands are swz8-pre-swizzled; GLD16 writes
// LDS linearly; reads XOR (fr&7).
// ===========================================================================
#define STAGE_A(kt, mh) do {                                              \
  const int p_ = (kt) & 1;                                                \
  _Pragma("unroll") for (int ld_ = 0; ld_ < 2; ++ld_) {                   \
    const int rl_ = (ld_ * 8 + wid) * 8 + (l >> 3);                       \
    GLD16(Ag + (size_t)((rl_ >> 6) * 128 + (mh) * 64 + (rl_ & 63)) * 1024 \
             + (kt) * 64 + (l & 7) * 8,                                   \
          &lds[p_ * 32768 + (mh) * 8192 + (ld_ * 8 + wid) * 512]);        \
  } } while (0)

#define STAGE_B(kt, nh) do {                                              \
  const int p_ = (kt) & 1;                                                \
  _Pragma("unroll") for (int ld_ = 0; ld_ < 2; ++ld_) {                   \
    const int rl_ = (ld_ * 8 + wid) * 8 + (l >> 3);                       \
    GLD16(Bg + (size_t)((rl_ >> 5) * 64 + (nh) * 32 + (rl_ & 31)) * 1024  \
             + (kt) * 64 + (l & 7) * 8,                                   \
          &lds[16384 + p_ * 32768 + (nh) * 8192 + (ld_ * 8 + wid) * 512]); \
  } } while (0)

#define PHASE(mh, nh, ...) do {                                           \
  if ((nh) == 0) {                                                        \
    _Pragma("unroll") for (int mi = 0; mi < 4; ++mi)                      \
      _Pragma("unroll") for (int ks = 0; ks < 2; ++ks)                    \
        afr[mi][ks] = *(const short8*)&lds[ab + (mh) * 8192               \
            + (wr * 64 + mi * 16 + fr) * 64                               \
            + (((ks * 4 + kg) ^ (fr & 7)) << 3)];                         \
  }                                                                       \
  _Pragma("unroll") for (int ni = 0; ni < 2; ++ni)                        \
    _Pragma("unroll") for (int ks = 0; ks < 2; ++ks)                      \
      bfrg[ni][ks] = *(const short8*)&lds[bb + (nh) * 8192                \
          + (wc * 32 + ni * 16 + fr) * 64                                 \
          + (((ks * 4 + kg) ^ (fr & 7)) << 3)];                           \
  __VA_ARGS__;                                                            \
  __builtin_amdgcn_s_barrier();                                           \
  __builtin_amdgcn_s_setprio(1);                                          \
  _Pragma("unroll") for (int mi = 0; mi < 4; ++mi)                        \
    _Pragma("unroll") for (int ni = 0; ni < 2; ++ni)                      \
      _Pragma("unroll") for (int ks = 0; ks < 2; ++ks)                    \
        acc[(mh) * 4 + mi][(nh) * 2 + ni] =                               \
            __builtin_amdgcn_mfma_f32_16x16x32_bf16(afr[mi][ks],          \
                bfrg[ni][ks], acc[(mh) * 4 + mi][(nh) * 2 + ni], 0, 0, 0); \
  __builtin_amdgcn_s_setprio(0);                                          \
} while (0)

#define KLOOP_8PHASE()                                                    \
  STAGE_A(0, 0); STAGE_B(0, 0); STAGE_B(0, 1); STAGE_A(0, 1);             \
  STAGE_A(1, 0); STAGE_B(1, 0);                                           \
  asm volatile("s_waitcnt vmcnt(4)" ::: "memory");                        \
  __builtin_amdgcn_s_barrier();                                           \
  _Pragma("unroll 2") for (int kt = 0; kt < 16; ++kt) {                   \
    const int ab = (kt & 1) * 32768;                                      \
    const int bb = 16384 + (kt & 1) * 32768;                              \
    PHASE(0, 0, if (kt < 15) STAGE_B(kt + 1, 1));                         \
    __builtin_amdgcn_s_barrier();                                         \
    PHASE(0, 1, if (kt < 15) STAGE_A(kt + 1, 1));                         \
    __builtin_amdgcn_s_barrier();                                         \
    PHASE(1, 0, if (kt < 14) STAGE_A(kt + 2, 0));                         \
    __builtin_amdgcn_s_barrier();                                         \
    PHASE(1, 1, if (kt < 14) STAGE_B(kt + 2, 0));                         \
    if (kt < 14) asm volatile("s_waitcnt vmcnt(4)" ::: "memory");         \
    else         asm volatile("s_waitcnt vmcnt(0)" ::: "memory");         \
    __builtin_amdgcn_s_barrier();                                         \
  }

// ---------------------------------------------------------------------------
// GEMM1 (8-phase): Xbf = bf16(exp(tanh(enc_bf . W2_bf^T + c1))) [swz8 layout]
// + atomic column sums.
// ---------------------------------------------------------------------------
__global__ __launch_bounds__(512) void energy8(const short* __restrict__ enc_bf,
                                               const short* __restrict__ W2_bf,
                                               const float* __restrict__ c1,
                                               short* __restrict__ Xbf,
                                               float* __restrict__ colsum) {
  __shared__ __align__(16) short lds[65536];   // 128 KB
  const int flat = blockIdx.x;
  const int id = (flat & 7) * 32 + (flat >> 3);   // XCD-chunked (256 = 8*32)
  const int b = id >> 4;
  const int row0 = ((id >> 2) & 3) * 256;
  const int col0 = (id & 3) * 256;
  const int t = threadIdx.x;
  const int wid = t >> 6, l = t & 63;
  const int wr = wid >> 2, wc = wid & 3;
  const int fr = l & 15, kg = l >> 4;

  const short* Ag = enc_bf + (size_t)b * SH + (size_t)row0 * 1024;
  const short* Bg = W2_bf + (size_t)col0 * 1024;

  f32x4 acc[8][4] = {};
  short8 afr[4][2], bfrg[2][2];

  KLOOP_8PHASE();
  __syncthreads();   // full fence before LDS reuse

  // epilogue: X = exp(tanh(acc+c1)); obuf bf16 (swz8-composed); colsum atomics
  unsigned short* obuf = (unsigned short*)lds;   // 256x256 ushort = 128 KB
#pragma unroll
  for (int n = 0; n < 4; ++n) {
    const int col_loc = wc * 64 + n * 16 + fr;
    const float c1v = c1[b * 1024 + col0 + col_loc];
    float csum = 0.f;
#pragma unroll
    for (int m = 0; m < 8; ++m) {
#pragma unroll
      for (int r = 0; r < 4; ++r) {
        const int row_loc = wr * 128 + m * 16 + kg * 4 + r;
        const float x = acc[m][n][r] + c1v;
        const float e = __expf(2.f * x);
        const float X = __expf((e - 1.f) / (e + 1.f));
        csum += X;
        const int g = col_loc >> 3;
        const int sg = (g & ~7) | ((g & 7) ^ (row_loc & 7));
        obuf[row_loc * 256 + sg * 8 + (col_loc & 7)] = (unsigned short)bfr(X);
      }
    }
    csum += __shfl_xor(csum, 16);
    csum += __shfl_xor(csum, 32);
    if (l < 16) atomicAdd(&colsum[b * 1024 + col0 + col_loc], csum);
  }
  __syncthreads();
  // linear copy-out (swizzles compose to global swz8 layout)
  const int orow = t >> 1;
  short* gd = Xbf + (size_t)b * SH + (size_t)(row0 + orow) * 1024 + col0;
#pragma unroll
  for (int j = 0; j < 16; ++j) {
    const int ls = (t & 1) * 16 + j;
    *(short8*)(gd + ls * 8) = *(short8*)&obuf[orow * 256 + ls * 8];
  }
}

// ---------------------------------------------------------------------------
// GEMM2 (8-phase): ctx = awbf . encT^T
// ---------------------------------------------------------------------------
__global__ __launch_bounds__(512) void context8(const short* __restrict__ awbf,
                                                const short* __restrict__ encT,
                                                float* __restrict__ ctx) {
  __shared__ __align__(16) short lds[65536];
  const int flat = blockIdx.x;
  const int id = (flat & 7) * 32 + (flat >> 3);
  const int b = id >> 4;
  const int row0 = ((id >> 2) & 3) * 256;
  const int col0 = (id & 3) * 256;
  const int t = threadIdx.x;
  const int wid = t >> 6, l = t & 63;
  const int wr = wid >> 2, wc = wid & 3;
  const int fr = l & 15, kg = l >> 4;

  const short* Ag = awbf + (size_t)b * SH + (size_t)row0 * 1024;
  const short* Bg = encT + (size_t)b * SH + (size_t)col0 * 1024;

  f32x4 acc[8][4] = {};
  short8 afr[4][2], bfrg[2][2];

  KLOOP_8PHASE();

  float* Cb = ctx + (size_t)b * SH;
#pragma unroll
  for (int n = 0; n < 4; ++n) {
    const int col = col0 + wc * 64 + n * 16 + fr;
#pragma unroll
    for (int m = 0; m < 8; ++m) {
#pragma unroll
      for (int r = 0; r < 4; ++r)
        Cb[(size_t)(row0 + wr * 128 + m * 16 + kg * 4 + r) * 1024 + col] = acc[m][n][r];
    }
  }
}

// ---------------------------------------------------------------------------
// rcp: colinv = 1/colsum
// ---------------------------------------------------------------------------
__global__ __launch_bounds__(256) void rcp_kernel(const float* __restrict__ cs,
                                                  float* __restrict__ ci) {
  const int i = blockIdx.x * 256 + threadIdx.x;
  ci[i] = 1.0f / cs[i];
}

// ---------------------------------------------------------------------------
// scale: awbf = bf16(Xbf * colinv) in-place (swz8, same slot), aw fp32 out
// ---------------------------------------------------------------------------
__global__ __launch_bounds__(256) void scale_v1(short* __restrict__ Xbf,
                                                const float* __restrict__ colinv,
                                                float* __restrict__ aw) {
  const size_t gid = (size_t)blockIdx.x * 256 + threadIdx.x;
  const int rg = (int)(gid >> 7);
  const int ss = (int)(gid & 127);
  const int b = rg >> 10;
  const int gl = (ss & ~7) | ((ss & 7) ^ (rg & 7));   // logical granule
  const int h0 = gl * 8;
  short* p = Xbf + (size_t)rg * 1024 + ss * 8;
  const short8 v = *(const short8*)p;
  const float4 ci0 = *(const float4*)(colinv + (b << 10) + h0);
  const float4 ci1 = *(const float4*)(colinv + (b << 10) + h0 + 4);
  float f[8];
  f[0] = b2f((unsigned short)v[0]) * ci0.x; f[1] = b2f((unsigned short)v[1]) * ci0.y;
  f[2] = b2f((unsigned short)v[2]) * ci0.z; f[3] = b2f((unsigned short)v[3]) * ci0.w;
  f[4] = b2f((unsigned short)v[4]) * ci1.x; f[5] = b2f((unsigned short)v[5]) * ci1.y;
  f[6] = b2f((unsigned short)v[6]) * ci1.z; f[7] = b2f((unsigned short)v[7]) * ci1.w;
  float4 o0 = {f[0], f[1], f[2], f[3]};
  float4 o1 = {f[4], f[5], f[6], f[7]};
  *(float4*)(aw + (size_t)rg * 1024 + h0) = o0;
  *(float4*)(aw + (size_t)rg * 1024 + h0 + 4) = o1;
  short8 r;
#pragma unroll
  for (int j = 0; j < 8; ++j) r[j] = bfr(f[j]);
  *(short8*)p = r;
}

// ===========================================================================
// Fallback path (no workspace needed): R6/R7-proven kernels
// ===========================================================================
__global__ __launch_bounds__(256) void energy_mfma4(const short* __restrict__ enc_bf,
                                                    const short* __restrict__ W2_bf,
                                                    const float* __restrict__ c1,
                                                    float* __restrict__ X) {
  __shared__ __align__(16) short Ast[128 * 64];
  __shared__ __align__(16) short Bst[128 * 64];
  const int flat = blockIdx.x + (blockIdx.y << 3) + (blockIdx.z << 6);
  const int swz = (flat & 7) * 128 + (flat >> 3);
  const int b = swz >> 6;
  const int row0 = ((swz >> 3) & 7) * 128;
  const int col0 = (swz & 7) * 128;
  const int t = threadIdx.x;
  const int l = t & 63;
  const int w = t >> 6;
  const int wr = w >> 1, wc = w & 1;
  const int fr = l & 15, kg = l >> 4;

  const short* Abase = enc_bf + (size_t)b * SH + (size_t)(row0 + w * 32 + (l >> 3)) * 1024 + (l & 7) * 8;
  const short* Bbase = W2_bf + (size_t)(col0 + w * 32 + (l >> 3)) * 1024 + (l & 7) * 8;
  short* Alds = Ast + w * 2048;
  short* Blds = Bst + w * 2048;

  f32x4 acc[4][4] = {};

  for (int k0 = 0; k0 < 1024; k0 += 64) {
#pragma unroll
    for (int j = 0; j < 4; ++j) {
      GLD16(Abase + k0 + j * 8 * 1024, Alds + j * 512);
      GLD16(Bbase + k0 + j * 8 * 1024, Blds + j * 512);
    }
    __syncthreads();
#pragma unroll
    for (int kk = 0; kk < 2; ++kk) {
      short8 af[4], bf4[4];
#pragma unroll
      for (int m = 0; m < 4; ++m) {
        const int r = wr * 64 + m * 16 + fr;
        af[m] = *(const short8*)&Ast[r * 64 + (((kk * 4 + kg) ^ (r & 7)) << 3)];
      }
#pragma unroll
      for (int n = 0; n < 4; ++n) {
        const int r = wc * 64 + n * 16 + fr;
        bf4[n] = *(const short8*)&Bst[r * 64 + (((kk * 4 + kg) ^ (r & 7)) << 3)];
      }
#pragma unroll
      for (int m = 0; m < 4; ++m)
#pragma unroll
        for (int n = 0; n < 4; ++n)
          acc[m][n] = __builtin_amdgcn_mfma_f32_16x16x32_bf16(af[m], bf4[n], acc[m][n], 0, 0, 0);
    }
    __syncthreads();
  }

  float* Xb = X + (size_t)b * SH;
#pragma unroll
  for (int n = 0; n < 4; ++n) {
    const int col = col0 + wc * 64 + n * 16 + fr;
    const float c1v = c1[b * 1024 + col];
#pragma unroll
    for (int m = 0; m < 4; ++m) {
      const int r0 = row0 + wr * 64 + m * 16 + kg * 4;
#pragma unroll
      for (int r = 0; r < 4; ++r) {
        const float x = acc[m][n][r] + c1v;
        const float e = __expf(2.f * x);
        Xb[(size_t)(r0 + r) * 1024 + col] = __expf((e - 1.f) / (e + 1.f));
      }
    }
  }
}

__global__ __launch_bounds__(256) void norm_kernel(float* __restrict__ X) {
  const int b = blockIdx.x >> 4;
  const int hg = blockIdx.x & 15;
  const int l = threadIdx.x & 63;
  const int sg = threadIdx.x >> 6;
  float* col = X + (size_t)b * SH + hg * 64 + l;
  const int s0 = sg * 256;
  float sum = 0.f;
#pragma unroll 8
  for (int s = s0; s < s0 + 256; ++s) sum += col[(size_t)s * 1024];
  __shared__ float red[4][64];
  red[sg][l] = sum;
  __syncthreads();
  const float inv = 1.f / (red[0][l] + red[1][l] + red[2][l] + red[3][l]);
#pragma unroll 8
  for (int s = s0; s < s0 + 256; ++s) col[(size_t)s * 1024] *= inv;
}

// self-contained fallback GEMM2 (raw fp32 inputs)
__global__ __launch_bounds__(256) void context_mfma(const float* __restrict__ aw,
                                                    const float* __restrict__ enc,
                                                    float* __restrict__ ctx) {
  __shared__ __align__(16) short Ast[128 * 32];
  __shared__ __align__(16) short Bst[128 * 32];
  const int b = blockIdx.z;
  const int row0 = blockIdx.y * 128;
  const int col0 = blockIdx.x * 128;
  const int t = threadIdx.x;
  const int l = t & 63;
  const int w = t >> 6;
  const int wr = w >> 1, wc = w & 1;
  const int fr = l & 15, kg = l >> 4;

  const int sr = t >> 1;
  const int sc0 = (t & 1) * 2;
  const float* arow = aw + (size_t)b * SH + (size_t)(row0 + sr) * 1024;
  const int bcol = t & 127;
  const int kb0 = (t >> 7) * 2;
  const float* bcolp = enc + (size_t)b * SH + col0 + bcol;

  f32x4 acc[4][4] = {};

#define LSLOT(r, g) ((r) * 32 + (((g) ^ (((r) >> 1) & 3)) << 3))
  for (int k0 = 0; k0 < 1024; k0 += 32) {
    const float4 a0 = *(const float4*)(arow + k0 + sc0 * 8);
    const float4 a1 = *(const float4*)(arow + k0 + sc0 * 8 + 4);
    const float4 a2 = *(const float4*)(arow + k0 + sc0 * 8 + 8);
    const float4 a3 = *(const float4*)(arow + k0 + sc0 * 8 + 12);
    float bv[2][8];
#pragma unroll
    for (int j = 0; j < 2; ++j)
#pragma unroll
      for (int i = 0; i < 8; ++i)
        bv[j][i] = bcolp[(size_t)(k0 + (kb0 + j) * 8 + i) * 1024];
    __syncthreads();
    *(short8*)&Ast[LSLOT(sr, sc0)]     = cvt8(a0, a1);
    *(short8*)&Ast[LSLOT(sr, sc0 + 1)] = cvt8(a2, a3);
#pragma unroll
    for (int j = 0; j < 2; ++j) {
      short8 pk;
#pragma unroll
      for (int i = 0; i < 8; ++i) pk[i] = bfr(bv[j][i]);
      *(short8*)&Bst[LSLOT(bcol, kb0 + j)] = pk;
    }
    __syncthreads();
    short8 af[4], bf4[4];
#pragma unroll
    for (int m = 0; m < 4; ++m) {
      const int r = wr * 64 + m * 16 + fr;
      af[m] = *(const short8*)&Ast[LSLOT(r, kg)];
    }
#pragma unroll
    for (int n = 0; n < 4; ++n) {
      const int r = wc * 64 + n * 16 + fr;
      bf4[n] = *(const short8*)&Bst[LSLOT(r, kg)];
    }
#pragma unroll
    for (int m = 0; m < 4; ++m)
#pragma unroll
      for (int n = 0; n < 4; ++n)
        acc[m][n] = __builtin_amdgcn_mfma_f32_16x16x32_bf16(af[m], bf4[n], acc[m][n], 0, 0, 0);
  }

  float* Cb = ctx + (size_t)b * SH;
#pragma unroll
  for (int n = 0; n < 4; ++n) {
    const int col = col0 + wc * 64 + n * 16 + fr;
#pragma unroll
    for (int m = 0; m < 4; ++m) {
      const int r0 = row0 + wr * 64 + m * 16 + kg * 4;
#pragma unroll
      for (int r = 0; r < 4; ++r)
        Cb[(size_t)(r0 + r) * 1024 + col] = acc[m][n][r];
    }
  }
}

// ---------------------------------------------------------------------------
extern "C" void kernel_launch(void* const* d_in, const int* in_sizes, int n_in,
                              void* d_out, int out_size, void* d_ws, size_t ws_size,
                              hipStream_t stream) {
  (void)in_sizes; (void)n_in; (void)out_size;
  const float* ht     = (const float*)d_in[0];
  const float* enc    = (const float*)d_in[1];
  const float* W_attn = (const float*)d_in[2];
  const float* b_attn = (const float*)d_in[3];
  // d_in[4] (W_v) is dead code in the reference

  float* ctx = (float*)d_out;          // [B,S,H] context (written last)
  float* aw  = ctx + BSH;              // [B,S,H] attention_weights

  // scratch parked inside the (dead-until-GEMM2) ctx region:
  short* enc_bf = (short*)ctx;                         // 32 MB, bf16 swz8
  short* W2_bf  = (short*)(ctx + 8388608);             // 2 MB
  float* c1f    = ctx + 8912896;                       // 64 KB
  float* colsum = c1f + 16384;                         // 64 KB
  float* colinv = c1f + 32768;                         // 64 KB

  const bool ws2 = ws_size >= ((size_t)64 << 20);      // encT + Xbf
  short* encT = (short*)d_ws;                          // 32 MB
  short* Xbf  = (short*)((char*)d_ws + ((size_t)32 << 20));  // 32 MB

  cvt_w2_kernel<<<512, 256, 0, stream>>>(W_attn, W2_bf);
  c1_kernel<<<Hn / 4, 256, 0, stream>>>(ht, W_attn, b_attn, c1f);

  if (ws2) {
    dim3 gt(16, 16, Bn);
    fused_cvt_kernel<<<gt, 256, 0, stream>>>(enc, enc_bf, encT);
    hipMemsetAsync(colsum, 0, 65536, stream);
    energy8<<<256, 512, 0, stream>>>(enc_bf, W2_bf, c1f, Xbf, colsum);
    rcp_kernel<<<64, 256, 0, stream>>>(colsum, colinv);
    scale_v1<<<8192, 256, 0, stream>>>(Xbf, colinv, aw);
    context8<<<256, 512, 0, stream>>>(Xbf, encT, ctx);
  } else {
    cvt_enc_kernel<<<8192, 256, 0, stream>>>(enc, enc_bf);
    dim3 g(8, 8, Bn);
    energy_mfma4<<<g, 256, 0, stream>>>(enc_bf, W2_bf, c1f, aw);
    norm_kernel<<<Bn * 16, 256, 0, stream>>>(aw);
    context_mfma<<<g, 256, 0, stream>>>(aw, enc, ctx);
  }
}